// Round 9
// baseline (605.637 us; speedup 1.0000x reference)
//
#include <hip/hip_runtime.h>

// Conv2d 5x5, C=3, O=1, stride 1, pad 2, N=256, H=W=224, +bias.
// R9: R7 geometry + R8 slim loads + a *feasible* launch_bounds cap.
//   R8 post-mortem: sched_barrier(0) does NOT bound pressure (VGPR stayed 128;
//   pressure target = amdgpu-waves-per-eu attr, set by launch_bounds arg 2)
//   and it cost ILP (67us). R7 at VGPR=128 = 4 waves/SIMD, latency-bound.
// Design:
//   - live set is small by construction: acc 28 (SY=7 x float4) + one step's
//     slim loads 24 + addr ~8 = ~60-68 VGPR; weights in SGPRs (SGPR=112).
//   - __launch_bounds__(256, 7): VGPR budget 512/7 = 73 -> allocator places
//     loads just-in-time instead of hoisting 3 steps deep. Feasible cap, so
//     no R2/R3-style spill expected (tripwire: WRITE_SIZE >> 50 MB = spill).
//   - SY=7, NSTRIP=32: 1792 blocks = exactly 7 blocks/CU; at VGPR<=73 all 7
//     resident simultaneously -> 28 waves/CU from t=0, zero round-quantization.
//   - slim loads: f2 @ x0-2, f4 @ x0, f2 @ x0+4 (all aligned; edge lanes
//     redirect masked loads inward, zeroed in window build -> no OOB).
//   - boundary row guards only on s in {0,1,SY+2,SY+3}; middle steps clean.

namespace {

constexpr int Hc = 224, Wc = 224, Cc = 3;
constexpr int HW = Hc * Wc;
constexpr int CHW = Cc * HW;
constexpr int TXv = 4;              // outputs per thread in x (float4)
constexpr int NCOL = Wc / TXv;      // 56
constexpr int SY = 7;               // strip height per thread
constexpr int NSTRIP = Hc / SY;     // 32
constexpr int BLK = 256;
constexpr int NSTEP = SY + 4;       // 11 input rows per strip

__global__ __launch_bounds__(BLK, 7) void conv5x5_r9(
    const float* __restrict__ x, const float* __restrict__ wl,
    const float* __restrict__ bptr, float* __restrict__ out) {
  const int t = blockIdx.x * BLK + threadIdx.x;
  // decode: col fastest (coalescing), then strip (pow2), then n
  const int col = t % NCOL;
  const int rest = t / NCOL;
  const int strip = rest & (NSTRIP - 1);
  const int n = rest >> 5;            // NSTRIP = 32

  const int x0 = col * TXv;
  const int y0 = strip * SY;
  const bool lo = (col == 0);          // left image edge lane
  const bool hi = (col == NCOL - 1);   // right image edge lane

  // Weights: wave-uniform, compile-time offsets -> s_load (SGPRs).
  float w[Cc][5][5];
#pragma unroll
  for (int c = 0; c < Cc; ++c)
#pragma unroll
    for (int i = 0; i < 25; ++i) w[c][i / 5][i % 5] = wl[c * 25 + i];
  const float bias = bptr[0];

  const float* xb = x + (size_t)n * CHW + x0;
  float* ob = out + (size_t)n * HW + x0;

  // Window floats needed: [x0-2, x0+5]. Loads: f2 @ x0-2 (8B-aligned,
  // x0%4==0), f4 @ x0 (16B), f2 @ x0+4 (8B). Edge lanes redirect the masked
  // load inward (values zeroed in window build) -> zero OOB accesses.
  const int dL = lo ? 0 : -2;
  const int dR = hi ? 0 : 4;

  float4 acc[SY];                      // statically indexed; <=5 live at once
#pragma unroll
  for (int o = 0; o < SY; ++o) acc[o] = make_float4(0.f, 0.f, 0.f, 0.f);

  // Input row s (yi = y0-2+s) feeds output rows o = s-ky, ky in [0,4].
  // acc[o]: born s=o, stored s=o+4. All indices compile-time after unroll.
#pragma unroll
  for (int s = 0; s < NSTEP; ++s) {
    const int yi = y0 + s - 2;
    // Middle steps s in [2, SY+1]: 0 <= yi <= y0+SY-1 <= 223 always.
    const bool boundary = (s < 2) || (s >= SY + 2);

    bool rv = true;
    int yc = yi;
    if (boundary) {
      rv = (yi >= 0) && (yi < Hc);
      yc = yi < 0 ? 0 : (yi >= Hc ? Hc - 1 : yi);     // clamp address
    }

    // This step's 9 slim loads, issued together (batched MLP within step).
    float2 Lh[Cc]; float4 Mv[Cc]; float2 Rh[Cc];
#pragma unroll
    for (int c = 0; c < Cc; ++c) {
      const float* pc = xb + (size_t)c * HW + (size_t)yc * Wc;
      Lh[c] = *(const float2*)(pc + dL);
      Mv[c] = *(const float4*)(pc);
      Rh[c] = *(const float2*)(pc + dR);
    }

#pragma unroll
    for (int c = 0; c < Cc; ++c) {
      const bool z = boundary && !rv;       // whole-row zero (y pad)
      float win[8];                          // win[j] = x[x0-2+j]
      win[0] = (z || lo) ? 0.f : Lh[c].x;
      win[1] = (z || lo) ? 0.f : Lh[c].y;
      win[2] = z ? 0.f : Mv[c].x;
      win[3] = z ? 0.f : Mv[c].y;
      win[4] = z ? 0.f : Mv[c].z;
      win[5] = z ? 0.f : Mv[c].w;
      win[6] = (z || hi) ? 0.f : Rh[c].x;
      win[7] = (z || hi) ? 0.f : Rh[c].y;
#pragma unroll
      for (int ky = 0; ky < 5; ++ky) {
        const int o = s - ky;
        if (o < 0 || o >= SY) continue;               // compile-time
#pragma unroll
        for (int kx = 0; kx < 5; ++kx) {
          const float wv = w[c][ky][kx];
          acc[o].x = fmaf(win[kx + 0], wv, acc[o].x);
          acc[o].y = fmaf(win[kx + 1], wv, acc[o].y);
          acc[o].z = fmaf(win[kx + 2], wv, acc[o].z);
          acc[o].w = fmaf(win[kx + 3], wv, acc[o].w);
        }
      }
    }

    if (s >= 4) {                     // output row s-4 complete
      float4 oo;
      oo.x = acc[s - 4].x + bias;
      oo.y = acc[s - 4].y + bias;
      oo.z = acc[s - 4].z + bias;
      oo.w = acc[s - 4].w + bias;
      *(float4*)(ob + (size_t)(y0 + s - 4) * Wc) = oo;
    }
  }
}

}  // namespace

extern "C" void kernel_launch(void* const* d_in, const int* in_sizes, int n_in,
                              void* d_out, int out_size, void* d_ws, size_t ws_size,
                              hipStream_t stream) {
  const float* x  = (const float*)d_in[0];   // [N,3,224,224] f32
  const float* wl = (const float*)d_in[1];   // [1,75] f32
  const float* b  = (const float*)d_in[2];   // [1] f32
  float* out = (float*)d_out;                // [N,224,224] f32

  const int N = out_size / HW;               // 256
  const int total = N * NSTRIP * NCOL;       // 458752
  const int nblk = total / BLK;              // 1792 = exactly 7 blocks/CU

  conv5x5_r9<<<nblk, BLK, 0, stream>>>(x, wl, b, out);
}

// Round 10
// 68.873 us; speedup vs baseline: 8.7936x; 8.7936x over previous
//
#include <hip/hip_runtime.h>

// Conv2d 5x5, C=3, O=1, stride 1, pad 2, N=256, H=W=224, +bias.
// R10: rolled software-pipelined walker (structural register-pressure control).
//   R9 post-mortem: launch_bounds min-waves arg is 3-for-3 catastrophic
//   (VGPR forced to 36, 843 MB spill writes). R8: sched_barrier doesn't bound
//   pressure (SSA renaming). R7 (full unroll): scheduler hoists load batches
//   -> VGPR 128 -> 4 waves/SIMD -> latency-bound at 55.5us.
//   The only reliable pressure bound is a ROLLED loop with loop-carried
//   named buffers: at most 2 row-batches live, ever.
// Structure:
//   - TXv=4 outputs/thread (lean VALU: ~90 ops/output incl. 1.5x halo)
//   - A/B double-buffered row loads; pipeline: ACC(X); store?; rotate;
//     reload X <- row s+2 (load-to-use distance = one 300-FMA step)
//   - acc ring acc0..acc4 (named, static); rotate costs 20 movs/step (7%)
//   - SY=8, NSTRIP=28: grid 1568 blocks = 6.125/CU; live set ~82-90 VGPR
//     -> 5-6 waves/SIMD resident
//   - slim loads f2@x0-2 / f4@x0 / f2@x0+4; edge lanes redirect inward,
//     zeroed in window build; OOB rows zero the whole buffer (y pad)

namespace {

constexpr int Hc = 224, Wc = 224, Cc = 3;
constexpr int HW = Hc * Wc;
constexpr int CHW = Cc * HW;
constexpr int TXv = 4;              // outputs per thread in x (float4)
constexpr int NCOL = Wc / TXv;      // 56
constexpr int SY = 8;               // strip height per thread
constexpr int NSTRIP = Hc / SY;     // 28
constexpr int BLK = 256;

__global__ __launch_bounds__(BLK) void conv5x5_r10(
    const float* __restrict__ x, const float* __restrict__ wl,
    const float* __restrict__ bptr, float* __restrict__ out) {
  const int t = blockIdx.x * BLK + threadIdx.x;
  // decode: col fastest (coalescing), then strip, then n
  const int col = t % NCOL;
  const int rest = t / NCOL;
  const int strip = rest % NSTRIP;
  const int n = rest / NSTRIP;

  const int x0 = col * TXv;
  const int y0 = strip * SY;
  const bool lo = (col == 0);          // left image edge lane
  const bool hi = (col == NCOL - 1);   // right image edge lane

  // Weights: wave-uniform, compile-time offsets -> s_load (SGPRs).
  float w[Cc][5][5];
#pragma unroll
  for (int c = 0; c < Cc; ++c)
#pragma unroll
    for (int i = 0; i < 25; ++i) w[c][i / 5][i % 5] = wl[c * 25 + i];
  const float bias = bptr[0];

  const float* xb = x + (size_t)n * CHW + x0;
  float* op = out + (size_t)n * HW + (size_t)y0 * Wc + x0;

  // Window = x[x0-2 .. x0+5]: f2 @ x0-2 (8B aligned), f4 @ x0 (16B),
  // f2 @ x0+4. Edge lanes redirect the masked load inward (zeroed later).
  const int dL = lo ? 0 : -2;
  const int dR = hi ? 0 : 4;

  float4 acc0 = make_float4(0.f, 0.f, 0.f, 0.f);
  float4 acc1 = acc0, acc2 = acc0, acc3 = acc0, acc4 = acc0;

  float2 LA[Cc], RA[Cc]; float4 MA[Cc];   // buffer A
  float2 LB[Cc], RB[Cc]; float4 MB[Cc];   // buffer B

#define LOADV(Lb, Mb, Rb, rowp)                                               \
  do {                                                                        \
    _Pragma("unroll") for (int c_ = 0; c_ < Cc; ++c_) {                       \
      const float* pc_ = (rowp) + (size_t)c_ * HW;                            \
      Lb[c_] = *(const float2*)(pc_ + dL);                                    \
      Mb[c_] = *(const float4*)(pc_);                                         \
      Rb[c_] = *(const float2*)(pc_ + dR);                                    \
    }                                                                         \
  } while (0)

#define ZEROB(Lb, Mb, Rb)                                                     \
  do {                                                                        \
    _Pragma("unroll") for (int c_ = 0; c_ < Cc; ++c_) {                       \
      Lb[c_] = make_float2(0.f, 0.f);                                         \
      Mb[c_] = make_float4(0.f, 0.f, 0.f, 0.f);                               \
      Rb[c_] = make_float2(0.f, 0.f);                                         \
    }                                                                         \
  } while (0)

  // Ring taps: acc_k holds the output row retiring in (4-k) more steps;
  // this input row contributes tap ky = 4-k to acc_k.
#define ACCUM(Lb, Mb, Rb)                                                     \
  do {                                                                        \
    _Pragma("unroll") for (int c_ = 0; c_ < Cc; ++c_) {                       \
      float win[8];                                                           \
      win[0] = lo ? 0.f : Lb[c_].x;                                           \
      win[1] = lo ? 0.f : Lb[c_].y;                                           \
      win[2] = Mb[c_].x;                                                      \
      win[3] = Mb[c_].y;                                                      \
      win[4] = Mb[c_].z;                                                      \
      win[5] = Mb[c_].w;                                                      \
      win[6] = hi ? 0.f : Rb[c_].x;                                           \
      win[7] = hi ? 0.f : Rb[c_].y;                                           \
      _Pragma("unroll") for (int kx_ = 0; kx_ < 5; ++kx_) {                   \
        const float w4_ = w[c_][4][kx_];                                      \
        acc0.x = fmaf(win[kx_ + 0], w4_, acc0.x);                             \
        acc0.y = fmaf(win[kx_ + 1], w4_, acc0.y);                             \
        acc0.z = fmaf(win[kx_ + 2], w4_, acc0.z);                             \
        acc0.w = fmaf(win[kx_ + 3], w4_, acc0.w);                             \
        const float w3_ = w[c_][3][kx_];                                      \
        acc1.x = fmaf(win[kx_ + 0], w3_, acc1.x);                             \
        acc1.y = fmaf(win[kx_ + 1], w3_, acc1.y);                             \
        acc1.z = fmaf(win[kx_ + 2], w3_, acc1.z);                             \
        acc1.w = fmaf(win[kx_ + 3], w3_, acc1.w);                             \
        const float w2_ = w[c_][2][kx_];                                      \
        acc2.x = fmaf(win[kx_ + 0], w2_, acc2.x);                             \
        acc2.y = fmaf(win[kx_ + 1], w2_, acc2.y);                             \
        acc2.z = fmaf(win[kx_ + 2], w2_, acc2.z);                             \
        acc2.w = fmaf(win[kx_ + 3], w2_, acc2.w);                             \
        const float w1_ = w[c_][1][kx_];                                      \
        acc3.x = fmaf(win[kx_ + 0], w1_, acc3.x);                             \
        acc3.y = fmaf(win[kx_ + 1], w1_, acc3.y);                             \
        acc3.z = fmaf(win[kx_ + 2], w1_, acc3.z);                             \
        acc3.w = fmaf(win[kx_ + 3], w1_, acc3.w);                             \
        const float w0_ = w[c_][0][kx_];                                      \
        acc4.x = fmaf(win[kx_ + 0], w0_, acc4.x);                             \
        acc4.y = fmaf(win[kx_ + 1], w0_, acc4.y);                             \
        acc4.z = fmaf(win[kx_ + 2], w0_, acc4.z);                             \
        acc4.w = fmaf(win[kx_ + 3], w0_, acc4.w);                             \
      }                                                                       \
    }                                                                         \
  } while (0)

#define ROT()                                                                 \
  do {                                                                        \
    acc0 = acc1; acc1 = acc2; acc2 = acc3; acc3 = acc4;                       \
    acc4 = make_float4(0.f, 0.f, 0.f, 0.f);                                   \
  } while (0)

#define STORE1()                                                              \
  do {                                                                        \
    float4 oo;                                                                \
    oo.x = acc0.x + bias; oo.y = acc0.y + bias;                               \
    oo.z = acc0.z + bias; oo.w = acc0.w + bias;                               \
    *(float4*)op = oo;                                                        \
    op += Wc;                                                                 \
  } while (0)

  // ---- prologue: rows y0-2, y0-1 (y-pad: zero the buffer if OOB) ----
  if (y0 - 2 >= 0) LOADV(LA, MA, RA, xb + (size_t)(y0 - 2) * Wc);
  else             ZEROB(LA, MA, RA);
  if (y0 - 1 >= 0) LOADV(LB, MB, RB, xb + (size_t)(y0 - 1) * Wc);
  else             ZEROB(LB, MB, RB);

  // ---- main rolled loop: steps 0..9 consume rows(0..9), load rows(2..11).
  // Step s consumes the buffer loaded 2 steps earlier, then reloads it with
  // row y0+s (= row(s+2)). Rows y0..y0+7 always valid; y0+8/y0+9 guarded.
  const float* q = xb + (size_t)y0 * Wc;
  int yl = y0;                               // row index loaded this step

#pragma unroll 1
  for (int s = 0; s < 10; s += 2) {
    // step s (even): consume A, reload A
    ACCUM(LA, MA, RA);
    if (s >= 4) STORE1();
    ROT();
    if (yl < Hc) LOADV(LA, MA, RA, q);
    else         ZEROB(LA, MA, RA);

    // step s+1: consume B, reload B
    ACCUM(LB, MB, RB);
    if (s >= 4) STORE1();                    // s+1>=4 <=> s>=4 (s even)
    ROT();
    if (yl + 1 < Hc) LOADV(LB, MB, RB, q + Wc);
    else             ZEROB(LB, MB, RB);

    q += 2 * Wc;
    yl += 2;
  }

  // ---- epilogue: steps 10, 11 (consume rows(10),(11); store rows 6,7) ----
  ACCUM(LA, MA, RA);
  STORE1();
  ROT();
  ACCUM(LB, MB, RB);
  STORE1();

#undef LOADV
#undef ZEROB
#undef ACCUM
#undef ROT
#undef STORE1
}

}  // namespace

extern "C" void kernel_launch(void* const* d_in, const int* in_sizes, int n_in,
                              void* d_out, int out_size, void* d_ws, size_t ws_size,
                              hipStream_t stream) {
  const float* x  = (const float*)d_in[0];   // [N,3,224,224] f32
  const float* wl = (const float*)d_in[1];   // [1,75] f32
  const float* b  = (const float*)d_in[2];   // [1] f32
  float* out = (float*)d_out;                // [N,224,224] f32

  const int N = out_size / HW;               // 256
  const int total = N * NSTRIP * NCOL;       // 401408
  const int nblk = total / BLK;              // 1568 blocks = 6.125 per CU

  conv5x5_r10<<<nblk, BLK, 0, stream>>>(x, wl, b, out);
}